// Round 4
// baseline (710.249 us; speedup 1.0000x reference)
//
#include <hip/hip_runtime.h>
#include <hip/hip_bf16.h>
#include <math.h>

#define N_NODES 20000
#define N_EDGES 480000
#define HIDDEN  128
#define ZDIM    384        // 2*HIDDEN + EDGE_FEAT
#define NOUT    256        // 2*HIDDEN
#define BN_EPS  1e-5f

#define LDZ 264            // 256 + 8 pad for z transpose tile

using bf16x8 = __attribute__((ext_vector_type(8))) short;
using f32x4  = __attribute__((ext_vector_type(4))) float;
using s16x4  = __attribute__((ext_vector_type(4))) short;

struct f32x8 { float4 a, b; };

__device__ __forceinline__ unsigned short f2b(float f) {
    union { float f; unsigned u; } v; v.f = f;
    unsigned r = v.u + 0x7fffu + ((v.u >> 16) & 1u);   // RTNE
    return (unsigned short)(r >> 16);
}
__device__ __forceinline__ float bflo(unsigned u) {
    union { unsigned x; float f; } v; v.x = u << 16; return v.f;
}
__device__ __forceinline__ float bfhi(unsigned u) {
    union { unsigned x; float f; } v; v.x = u & 0xffff0000u; return v.f;
}
__device__ __forceinline__ float b2f(unsigned short s) {
    union { unsigned u; float f; } v; v.u = ((unsigned)s) << 16; return v.f;
}
__device__ __forceinline__ float sigmoid_(float x) {
    return 1.f / (1.f + __expf(-x));
}
__device__ __forceinline__ float softplus_(float x) {
    return fmaxf(x, 0.f) + __logf(1.f + __expf(-fabsf(x)));
}
__device__ __forceinline__ f32x8 ld8(const float* p) {
    f32x8 r; r.a = *(const float4*)p; r.b = *(const float4*)(p + 4); return r;
}
__device__ __forceinline__ bf16x8 cvt8(f32x8 v) {
    bf16x8 pk;
    pk[0] = (short)f2b(v.a.x); pk[1] = (short)f2b(v.a.y);
    pk[2] = (short)f2b(v.a.z); pk[3] = (short)f2b(v.a.w);
    pk[4] = (short)f2b(v.b.x); pk[5] = (short)f2b(v.b.y);
    pk[6] = (short)f2b(v.b.z); pk[7] = (short)f2b(v.b.w);
    return pk;
}

// ---- W [384][256] f32  ->  Wt [256][384] bf16 ----------------------------
__global__ void convW(const float* __restrict__ W, short* __restrict__ wt) {
    int n = blockIdx.x;
    for (int k = threadIdx.x; k < ZDIM; k += 256)
        wt[n * ZDIM + k] = (short)f2b(W[(size_t)k * NOUT + n]);
}

// ---- BN stats -> scale/shift ---------------------------------------------
__global__ void bn_finalize(const float* __restrict__ stats,
                            const float* __restrict__ gamma,
                            const float* __restrict__ beta,
                            float* __restrict__ scaleC,
                            float* __restrict__ shiftC) {
    int c = threadIdx.x;
    float s = 0.f, q = 0.f;
    for (int p = 0; p < 64; ++p) {
        s += stats[p * 512 + c];
        q += stats[p * 512 + 256 + c];
    }
    const float invE = 1.f / (float)N_EDGES;
    float m   = s * invE;                    // linear bias b cancels in BN
    float var = q * invE - m * m;
    float inv = rsqrtf(var + BN_EPS);
    float sc  = gamma[c] * inv;
    scaleC[c] = sc;
    shiftC[c] = beta[c] - m * sc;
}

// ---- counting sort of edges by dst ---------------------------------------
__global__ void hist_dst(const int* __restrict__ dst, int* __restrict__ counts) {
    int i = blockIdx.x * 256 + threadIdx.x;
    if (i < N_EDGES) atomicAdd(&counts[dst[i]], 1);
}

__global__ void scan_nodes(const int* __restrict__ counts, int* __restrict__ offs,
                           int* __restrict__ cursor) {
    __shared__ int part[1024];
    int t = threadIdx.x;
    int base = t * 20;
    int local[20]; int s = 0;
    #pragma unroll
    for (int k = 0; k < 20; ++k) {
        int idx = base + k;
        int v = (idx < N_NODES) ? counts[idx] : 0;
        local[k] = s; s += v;
    }
    part[t] = s; __syncthreads();
    for (int d = 1; d < 1024; d <<= 1) {
        int v = (t >= d) ? part[t - d] : 0;
        __syncthreads();
        part[t] += v;
        __syncthreads();
    }
    int pre = (t > 0) ? part[t - 1] : 0;
    #pragma unroll
    for (int k = 0; k < 20; ++k) {
        int idx = base + k;
        if (idx < N_NODES) { int o = pre + local[k]; offs[idx] = o; cursor[idx] = o; }
    }
}

__global__ void build_perm(const int* __restrict__ dst, int* __restrict__ cursor,
                           int* __restrict__ perm) {
    int i = blockIdx.x * 256 + threadIdx.x;
    if (i < N_EDGES) { int p = atomicAdd(&cursor[dst[i]], 1); perm[p] = i; }
}

// ---- edge GEMM: A-fragments gathered straight from global ----------------
// MODE 0: stats + raw-z bf16 write (main)
// MODE 1: stats only (fallback)   MODE 2: normalize+gate+atomic scatter (fallback)
template<int MODE>
__global__ __launch_bounds__(256)
void edge_gemm(const float* __restrict__ h, const float* __restrict__ e,
               const int* __restrict__ src, const int* __restrict__ dst,
               const short* __restrict__ wt,
               float* __restrict__ stats,
               const float* __restrict__ scaleC, const float* __restrict__ shiftC,
               float* __restrict__ agg, short* __restrict__ zout) {
    const int tid  = threadIdx.x;
    const int bm   = blockIdx.x;
    const int rowBase = bm * 64;
    const int lane = tid & 63;
    const int brow = lane & 15;
    const int kgo  = (lane >> 4) * 8;        // k offset within 32-chunk
    const int wcol = (tid >> 6) * 64;

    __shared__ __align__(16) short lds[64 * LDZ];   // z transpose tile (33.8 KB)

    // per-lane row indices for the 4 m-fragments
    const float* aB0[4];   // h[src[row]] region (k 0..127)
    const float* aB1[4];   // h[dst[row]] region (k 128..255)
    const float* aB2[4];   // e[row]      region (k 256..383)
    #pragma unroll
    for (int m = 0; m < 4; ++m) {
        int row = rowBase + m * 16 + brow;
        aB0[m] = h + (size_t)src[row] * HIDDEN + kgo;
        aB1[m] = h + (size_t)dst[row] * HIDDEN + kgo;
        aB2[m] = e + (size_t)row * HIDDEN + kgo;
    }
    const short* wB[4];
    #pragma unroll
    for (int n = 0; n < 4; ++n)
        wB[n] = wt + (size_t)(wcol + n * 16 + brow) * ZDIM + kgo;

    // A pointer for K-step kk (kk compile-time under full unroll)
    #define APTR(m, kk) ((kk) < 4 ? aB0[m] + (kk) * 32 \
                       : (kk) < 8 ? aB1[m] + ((kk) - 4) * 32 \
                                  : aB2[m] + ((kk) - 8) * 32)

    f32x4 acc[4][4] = {};
    bf16x8 aC[4], bC[4];
    #pragma unroll
    for (int m = 0; m < 4; ++m) aC[m] = cvt8(ld8(APTR(m, 0)));
    #pragma unroll
    for (int n = 0; n < 4; ++n) bC[n] = *(const bf16x8*)(wB[n]);

    #pragma unroll
    for (int kk = 0; kk < 12; ++kk) {
        bf16x8 aN[4], bN[4];
        if (kk < 11) {
            #pragma unroll
            for (int n = 0; n < 4; ++n)
                bN[n] = *(const bf16x8*)(wB[n] + (kk + 1) * 32);
            #pragma unroll
            for (int m = 0; m < 4; ++m)
                aN[m] = cvt8(ld8(APTR(m, kk + 1)));
        }
        #pragma unroll
        for (int m = 0; m < 4; ++m)
            #pragma unroll
            for (int n = 0; n < 4; ++n)
                acc[m][n] = __builtin_amdgcn_mfma_f32_16x16x32_bf16(
                                aC[m], bC[n], acc[m][n], 0, 0, 0);
        if (kk < 11) {
            #pragma unroll
            for (int m = 0; m < 4; ++m) aC[m] = aN[m];
            #pragma unroll
            for (int n = 0; n < 4; ++n) bC[n] = bN[n];
        }
    }
    #undef APTR

    if (MODE == 0 || MODE == 1) {
        // per-column sum/sumsq, 64-way-split atomics
        float* base = stats + (size_t)(bm & 63) * 512;
        #pragma unroll
        for (int n = 0; n < 4; ++n) {
            float s = 0.f, q = 0.f;
            #pragma unroll
            for (int m = 0; m < 4; ++m)
                #pragma unroll
                for (int r = 0; r < 4; ++r) {
                    float v = acc[m][n][r];
                    s += v; q += v * v;
                }
            s += __shfl_xor(s, 16, 64); s += __shfl_xor(s, 32, 64);
            q += __shfl_xor(q, 16, 64); q += __shfl_xor(q, 32, 64);
            if (lane < 16) {
                int col = wcol + n * 16 + lane;
                atomicAdd(base + col, s);
                atomicAdd(base + 256 + col, q);
            }
        }
    }

    if (MODE == 0) {
        // raw z -> bf16 transpose tile in LDS -> coalesced global write
        #pragma unroll
        for (int m = 0; m < 4; ++m) {
            int rowb = m * 16 + (lane >> 4) * 4;
            #pragma unroll
            for (int n = 0; n < 4; ++n) {
                int col = wcol + n * 16 + brow;
                #pragma unroll
                for (int r = 0; r < 4; ++r)
                    lds[(rowb + r) * LDZ + col] = (short)f2b(acc[m][n][r]);
            }
        }
        __syncthreads();
        #pragma unroll
        for (int it = 0; it < 8; ++it) {
            int chunk = tid + it * 256;
            int r = chunk >> 5;
            int c = (chunk & 31) * 8;
            *(bf16x8*)&zout[((size_t)rowBase + r) * NOUT + c] =
                *(const bf16x8*)&lds[r * LDZ + c];
        }
    }

    if (MODE == 2) {
        float sc[4], sh[4];
        #pragma unroll
        for (int n = 0; n < 4; ++n) {
            int col = wcol + n * 16 + brow;
            sc[n] = scaleC[col];
            sh[n] = shiftC[col];
        }
        #pragma unroll
        for (int m = 0; m < 4; ++m) {
            int rowb = m * 16 + (lane >> 4) * 4;
            #pragma unroll
            for (int n = 0; n < 4; ++n) {
                int col = wcol + n * 16 + brow;
                #pragma unroll
                for (int r = 0; r < 4; ++r) {
                    float zn = acc[m][n][r] * sc[n] + sh[n];
                    lds[(rowb + r) * LDZ + col] = (short)f2b(zn);
                }
            }
        }
        __syncthreads();
        const int c0 = (tid & 31) * 4;
        const int r0 = tid >> 5;
        #pragma unroll
        for (int rp = 0; rp < 8; ++rp) {
            int row = rp * 8 + r0;
            int d   = dst[rowBase + row];
            float* ap = agg + (size_t)d * HIDDEN + c0;
            s16x4 f4 = *(const s16x4*)&lds[row * LDZ + c0];
            s16x4 c4 = *(const s16x4*)&lds[row * LDZ + 128 + c0];
            #pragma unroll
            for (int j = 0; j < 4; ++j) {
                float fv  = b2f((unsigned short)f4[j]);
                float cv  = b2f((unsigned short)c4[j]);
                atomicAdd(ap + j, sigmoid_(fv) * softplus_(cv));
            }
        }
    }
}

// ---- per-node gather-reduce: normalize + gate + segment-sum + residual ----
__global__ __launch_bounds__(256)
void node_gather(const short* __restrict__ z, const int* __restrict__ perm,
                 const int* __restrict__ offs, const int* __restrict__ counts,
                 const float* __restrict__ scaleC, const float* __restrict__ shiftC,
                 const float* __restrict__ h, float* __restrict__ out) {
    int node = blockIdx.x * 4 + (threadIdx.x >> 6);
    int lane = threadIdx.x & 63;
    int l32  = lane & 31;
    int c0   = l32 * 4;

    float scF[4], shF[4], scS[4], shS[4];
    #pragma unroll
    for (int k = 0; k < 4; ++k) {
        scF[k] = scaleC[c0 + k];       shF[k] = shiftC[c0 + k];
        scS[k] = scaleC[128 + c0 + k]; shS[k] = shiftC[128 + c0 + k];
    }

    int s   = offs[node];
    int deg = counts[node];
    float a0 = 0.f, a1 = 0.f, a2 = 0.f, a3 = 0.f;

    for (int j = (lane >> 5); j < deg; j += 4) {
        int jB = j + 2;
        bool hasB = (jB < deg);
        int eA = perm[s + j];
        int eB = hasB ? perm[s + jB] : eA;
        const short* zA = z + (size_t)eA * NOUT + c0;
        const short* zB = z + (size_t)eB * NOUT + c0;
        uint2 fA = *(const uint2*)zA;
        uint2 cA = *(const uint2*)(zA + 128);
        uint2 fB = *(const uint2*)zB;
        uint2 cB = *(const uint2*)(zB + 128);

        float f0 = bflo(fA.x) * scF[0] + shF[0];
        float f1 = bfhi(fA.x) * scF[1] + shF[1];
        float f2 = bflo(fA.y) * scF[2] + shF[2];
        float f3 = bfhi(fA.y) * scF[3] + shF[3];
        float g0 = bflo(cA.x) * scS[0] + shS[0];
        float g1 = bfhi(cA.x) * scS[1] + shS[1];
        float g2 = bflo(cA.y) * scS[2] + shS[2];
        float g3 = bfhi(cA.y) * scS[3] + shS[3];
        a0 += sigmoid_(f0) * softplus_(g0);
        a1 += sigmoid_(f1) * softplus_(g1);
        a2 += sigmoid_(f2) * softplus_(g2);
        a3 += sigmoid_(f3) * softplus_(g3);

        if (hasB) {
            f0 = bflo(fB.x) * scF[0] + shF[0];
            f1 = bfhi(fB.x) * scF[1] + shF[1];
            f2 = bflo(fB.y) * scF[2] + shF[2];
            f3 = bfhi(fB.y) * scF[3] + shF[3];
            g0 = bflo(cB.x) * scS[0] + shS[0];
            g1 = bfhi(cB.x) * scS[1] + shS[1];
            g2 = bflo(cB.y) * scS[2] + shS[2];
            g3 = bfhi(cB.y) * scS[3] + shS[3];
            a0 += sigmoid_(f0) * softplus_(g0);
            a1 += sigmoid_(f1) * softplus_(g1);
            a2 += sigmoid_(f2) * softplus_(g2);
            a3 += sigmoid_(f3) * softplus_(g3);
        }
    }
    a0 += __shfl_xor(a0, 32, 64);
    a1 += __shfl_xor(a1, 32, 64);
    a2 += __shfl_xor(a2, 32, 64);
    a3 += __shfl_xor(a3, 32, 64);

    if (lane < 32) {
        size_t o = (size_t)node * HIDDEN + c0;
        float4 hv = *(const float4*)&h[o];
        float4 r;
        r.x = softplus_(hv.x + a0);
        r.y = softplus_(hv.y + a1);
        r.z = softplus_(hv.z + a2);
        r.w = softplus_(hv.w + a3);
        *(float4*)&out[o] = r;
    }
}

// ---- fallback finalize ----------------------------------------------------
__global__ void node_finalize(const float* __restrict__ h, float* __restrict__ out) {
    int i = blockIdx.x * 256 + threadIdx.x;
    float4 hv = ((const float4*)h)[i];
    float4 av = ((float4*)out)[i];
    float4 r;
    r.x = softplus_(hv.x + av.x);
    r.y = softplus_(hv.y + av.y);
    r.z = softplus_(hv.z + av.z);
    r.w = softplus_(hv.w + av.w);
    ((float4*)out)[i] = r;
}

extern "C" void kernel_launch(void* const* d_in, const int* in_sizes, int n_in,
                              void* d_out, int out_size, void* d_ws, size_t ws_size,
                              hipStream_t stream) {
    const float* h     = (const float*)d_in[0];
    const float* e     = (const float*)d_in[1];
    const int*   srcp  = (const int*)d_in[2];
    const int*   dstp  = (const int*)d_in[3];
    const float* W     = (const float*)d_in[4];
    // d_in[5] = b : cancels through BatchNorm
    const float* gamma = (const float*)d_in[6];
    const float* beta  = (const float*)d_in[7];
    float* out = (float*)d_out;

    char*  ws     = (char*)d_ws;
    float* stats  = (float*)ws;                  // 64*512*4 = 131072 B
    float* scaleC = (float*)(ws + 131072);
    float* shiftC = (float*)(ws + 132096);
    short* wt     = (short*)(ws + 133120);       // 196608 B -> 329728
    int*   counts = (int*)(ws + 329728);
    int*   offs   = (int*)(ws + 409856);
    int*   cursor = (int*)(ws + 489984);
    int*   perm   = (int*)(ws + 570112);         // 1.92 MB -> 2490112
    short* zbuf   = (short*)(ws + 2490112);      // 245.76 MB
    const size_t need = 2490112ull + (size_t)N_EDGES * NOUT * 2;

    hipMemsetAsync(stats, 0, 131072, stream);
    convW<<<NOUT, 256, 0, stream>>>(W, wt);

    if (ws_size >= need) {
        hipMemsetAsync(counts, 0, N_NODES * sizeof(int), stream);
        hist_dst<<<(N_EDGES + 255) / 256, 256, 0, stream>>>(dstp, counts);
        scan_nodes<<<1, 1024, 0, stream>>>(counts, offs, cursor);
        build_perm<<<(N_EDGES + 255) / 256, 256, 0, stream>>>(dstp, cursor, perm);

        edge_gemm<0><<<N_EDGES / 64, 256, 0, stream>>>(h, e, srcp, dstp, wt,
                stats, nullptr, nullptr, nullptr, zbuf);
        bn_finalize<<<1, 256, 0, stream>>>(stats, gamma, beta, scaleC, shiftC);
        node_gather<<<N_NODES / 4, 256, 0, stream>>>(zbuf, perm, offs, counts,
                scaleC, shiftC, h, out);
    } else {
        hipMemsetAsync(out, 0, (size_t)N_NODES * HIDDEN * sizeof(float), stream);
        edge_gemm<1><<<N_EDGES / 64, 256, 0, stream>>>(h, e, srcp, dstp, wt,
                stats, nullptr, nullptr, nullptr, nullptr);
        bn_finalize<<<1, 256, 0, stream>>>(stats, gamma, beta, scaleC, shiftC);
        edge_gemm<2><<<N_EDGES / 64, 256, 0, stream>>>(h, e, srcp, dstp, wt,
                stats, scaleC, shiftC, out, nullptr);
        node_finalize<<<N_NODES * HIDDEN / (4 * 256), 256, 0, stream>>>(h, out);
    }
}

// Round 5
// 605.787 us; speedup vs baseline: 1.1724x; 1.1724x over previous
//
#include <hip/hip_runtime.h>
#include <hip/hip_bf16.h>
#include <math.h>

#define N_NODES 20000
#define N_EDGES 480000
#define HIDDEN  128
#define ZDIM    384        // 2*HIDDEN + EDGE_FEAT
#define NOUT    256        // 2*HIDDEN
#define BN_EPS  1e-5f

#define LDZ 264            // 256 + 8 pad; used for BOTH the h-tile and z-transpose tile

using bf16x8 = __attribute__((ext_vector_type(8))) short;
using f32x4  = __attribute__((ext_vector_type(4))) float;
using s16x4  = __attribute__((ext_vector_type(4))) short;

struct f32x8 { float4 a, b; };

__device__ __forceinline__ unsigned short f2b(float f) {
    union { float f; unsigned u; } v; v.f = f;
    unsigned r = v.u + 0x7fffu + ((v.u >> 16) & 1u);   // RTNE
    return (unsigned short)(r >> 16);
}
__device__ __forceinline__ float bflo(unsigned u) {
    union { unsigned x; float f; } v; v.x = u << 16; return v.f;
}
__device__ __forceinline__ float bfhi(unsigned u) {
    union { unsigned x; float f; } v; v.x = u & 0xffff0000u; return v.f;
}
__device__ __forceinline__ float b2f(unsigned short s) {
    union { unsigned u; float f; } v; v.u = ((unsigned)s) << 16; return v.f;
}
__device__ __forceinline__ float sigmoid_(float x) {
    return 1.f / (1.f + __expf(-x));
}
__device__ __forceinline__ float softplus_(float x) {
    return fmaxf(x, 0.f) + __logf(1.f + __expf(-fabsf(x)));
}
__device__ __forceinline__ f32x8 ld8(const float* p) {
    f32x8 r; r.a = *(const float4*)p; r.b = *(const float4*)(p + 4); return r;
}
__device__ __forceinline__ bf16x8 cvt8(f32x8 v) {
    bf16x8 pk;
    pk[0] = (short)f2b(v.a.x); pk[1] = (short)f2b(v.a.y);
    pk[2] = (short)f2b(v.a.z); pk[3] = (short)f2b(v.a.w);
    pk[4] = (short)f2b(v.b.x); pk[5] = (short)f2b(v.b.y);
    pk[6] = (short)f2b(v.b.z); pk[7] = (short)f2b(v.b.w);
    return pk;
}

// ---- W [384][256] f32  ->  Wt [256][384] bf16 ----------------------------
__global__ void convW(const float* __restrict__ W, short* __restrict__ wt) {
    int n = blockIdx.x;
    for (int k = threadIdx.x; k < ZDIM; k += 256)
        wt[n * ZDIM + k] = (short)f2b(W[(size_t)k * NOUT + n]);
}

// ---- BN stats -> scale/shift ---------------------------------------------
__global__ void bn_finalize(const float* __restrict__ stats,
                            const float* __restrict__ gamma,
                            const float* __restrict__ beta,
                            float* __restrict__ scaleC,
                            float* __restrict__ shiftC) {
    int c = threadIdx.x;
    float s = 0.f, q = 0.f;
    for (int p = 0; p < 64; ++p) {
        s += stats[p * 512 + c];
        q += stats[p * 512 + 256 + c];
    }
    const float invE = 1.f / (float)N_EDGES;
    float m   = s * invE;                    // linear bias b cancels in BN
    float var = q * invE - m * m;
    float inv = rsqrtf(var + BN_EPS);
    float sc  = gamma[c] * inv;
    scaleC[c] = sc;
    shiftC[c] = beta[c] - m * sc;
}

// ---- counting sort of edges by dst ---------------------------------------
__global__ void hist_dst(const int* __restrict__ dst, int* __restrict__ counts) {
    int i = blockIdx.x * 256 + threadIdx.x;
    if (i < N_EDGES) atomicAdd(&counts[dst[i]], 1);
}

__global__ void scan_nodes(const int* __restrict__ counts, int* __restrict__ offs,
                           int* __restrict__ cursor) {
    __shared__ int part[1024];
    int t = threadIdx.x;
    int base = t * 20;
    int local[20]; int s = 0;
    #pragma unroll
    for (int k = 0; k < 20; ++k) {
        int idx = base + k;
        int v = (idx < N_NODES) ? counts[idx] : 0;
        local[k] = s; s += v;
    }
    part[t] = s; __syncthreads();
    for (int d = 1; d < 1024; d <<= 1) {
        int v = (t >= d) ? part[t - d] : 0;
        __syncthreads();
        part[t] += v;
        __syncthreads();
    }
    int pre = (t > 0) ? part[t - 1] : 0;
    #pragma unroll
    for (int k = 0; k < 20; ++k) {
        int idx = base + k;
        if (idx < N_NODES) { int o = pre + local[k]; offs[idx] = o; cursor[idx] = o; }
    }
}

__global__ void build_perm(const int* __restrict__ dst, int* __restrict__ cursor,
                           int* __restrict__ perm) {
    int i = blockIdx.x * 256 + threadIdx.x;
    if (i < N_EDGES) { int p = atomicAdd(&cursor[dst[i]], 1); perm[p] = i; }
}

// ---- edge GEMM: h staged in LDS (shared), e pre-fetched per-lane ---------
// MODE 0: stats + raw-z bf16 write (main)
// MODE 1: stats only (fallback)   MODE 2: normalize+gate+atomic scatter (fallback)
template<int MODE>
__global__ __launch_bounds__(256, 2)
void edge_gemm(const float* __restrict__ h, const float* __restrict__ e,
               const int* __restrict__ src, const int* __restrict__ dst,
               const short* __restrict__ wt,
               float* __restrict__ stats,
               const float* __restrict__ scaleC, const float* __restrict__ shiftC,
               float* __restrict__ agg, short* __restrict__ zout) {
    const int tid  = threadIdx.x;
    const int bm   = blockIdx.x;
    const int rowBase = bm * 64;
    const int lane = tid & 63;
    const int brow = lane & 15;
    const int kgo  = (lane >> 4) * 8;        // k offset within 32-chunk
    const int wcol = (tid >> 6) * 64;

    __shared__ __align__(16) short lds[64 * LDZ];   // 33792 B: h-tile, then z-tile

    // ---- 1. issue ALL e loads first (HBM latency hides under staging) ----
    const float* eP[4];
    #pragma unroll
    for (int m = 0; m < 4; ++m)
        eP[m] = e + (size_t)(rowBase + m * 16 + brow) * HIDDEN + kgo;
    f32x8 eF[4][4];
    #pragma unroll
    for (int s = 0; s < 4; ++s)
        #pragma unroll
        for (int m = 0; m < 4; ++m)
            eF[s][m] = ld8(eP[m] + s * 32);

    // ---- 2. stage h_src|h_dst tile: 64 rows x 256 feats -> LDS bf16 ----
    #pragma unroll
    for (int it = 0; it < 8; ++it) {
        int u   = tid + it * 256;            // 2048 chunks: 32 per row
        int r   = u >> 5;
        int f0  = (u & 31) * 8;
        int row = rowBase + r;
        const float* p = (f0 < 128) ? h + (size_t)src[row] * HIDDEN + f0
                                    : h + (size_t)dst[row] * HIDDEN + (f0 - 128);
        *(bf16x8*)&lds[r * LDZ + f0] = cvt8(ld8(p));
    }

    // ---- 3. convert e to bf16 fragments (data arrived during staging) ----
    bf16x8 aE[4][4];
    #pragma unroll
    for (int s = 0; s < 4; ++s)
        #pragma unroll
        for (int m = 0; m < 4; ++m)
            aE[s][m] = cvt8(eF[s][m]);

    __syncthreads();

    // ---- 4. K loop: steps 0-7 from LDS, steps 8-11 from aE ----
    const short* wB[4];
    #pragma unroll
    for (int n = 0; n < 4; ++n)
        wB[n] = wt + (size_t)(wcol + n * 16 + brow) * ZDIM + kgo;

    f32x4 acc[4][4] = {};
    bf16x8 aC[4], bC[4];
    #pragma unroll
    for (int m = 0; m < 4; ++m)
        aC[m] = *(const bf16x8*)&lds[(m * 16 + brow) * LDZ + kgo];
    #pragma unroll
    for (int n = 0; n < 4; ++n) bC[n] = *(const bf16x8*)(wB[n]);

    #pragma unroll
    for (int kk = 0; kk < 12; ++kk) {
        bf16x8 aN[4], bN[4];
        if (kk < 7) {
            #pragma unroll
            for (int m = 0; m < 4; ++m)
                aN[m] = *(const bf16x8*)&lds[(m * 16 + brow) * LDZ + (kk + 1) * 32 + kgo];
        }
        if (kk < 11) {
            #pragma unroll
            for (int n = 0; n < 4; ++n)
                bN[n] = *(const bf16x8*)(wB[n] + (kk + 1) * 32);
        }
        #pragma unroll
        for (int m = 0; m < 4; ++m) {
            bf16x8 af = (kk < 8) ? aC[m] : aE[(kk >= 8) ? (kk - 8) : 0][m];
            #pragma unroll
            for (int n = 0; n < 4; ++n)
                acc[m][n] = __builtin_amdgcn_mfma_f32_16x16x32_bf16(
                                af, bC[n], acc[m][n], 0, 0, 0);
        }
        if (kk < 7) {
            #pragma unroll
            for (int m = 0; m < 4; ++m) aC[m] = aN[m];
        }
        if (kk < 11) {
            #pragma unroll
            for (int n = 0; n < 4; ++n) bC[n] = bN[n];
        }
    }

    if (MODE == 0 || MODE == 1) {
        // per-column sum/sumsq, 64-way-split atomics
        float* base = stats + (size_t)(bm & 63) * 512;
        #pragma unroll
        for (int n = 0; n < 4; ++n) {
            float s = 0.f, q = 0.f;
            #pragma unroll
            for (int m = 0; m < 4; ++m)
                #pragma unroll
                for (int r = 0; r < 4; ++r) {
                    float v = acc[m][n][r];
                    s += v; q += v * v;
                }
            s += __shfl_xor(s, 16, 64); s += __shfl_xor(s, 32, 64);
            q += __shfl_xor(q, 16, 64); q += __shfl_xor(q, 32, 64);
            if (lane < 16) {
                int col = wcol + n * 16 + lane;
                atomicAdd(base + col, s);
                atomicAdd(base + 256 + col, q);
            }
        }
    }

    if (MODE == 0) {
        // raw z -> bf16 transpose tile in LDS -> coalesced global write
        __syncthreads();                      // everyone done reading h-tile
        #pragma unroll
        for (int m = 0; m < 4; ++m) {
            int rowb = m * 16 + (lane >> 4) * 4;
            #pragma unroll
            for (int n = 0; n < 4; ++n) {
                int col = wcol + n * 16 + brow;
                #pragma unroll
                for (int r = 0; r < 4; ++r)
                    lds[(rowb + r) * LDZ + col] = (short)f2b(acc[m][n][r]);
            }
        }
        __syncthreads();
        #pragma unroll
        for (int it = 0; it < 8; ++it) {
            int chunk = tid + it * 256;
            int r = chunk >> 5;
            int c = (chunk & 31) * 8;
            *(bf16x8*)&zout[((size_t)rowBase + r) * NOUT + c] =
                *(const bf16x8*)&lds[r * LDZ + c];
        }
    }

    if (MODE == 2) {
        float sc[4], sh[4];
        #pragma unroll
        for (int n = 0; n < 4; ++n) {
            int col = wcol + n * 16 + brow;
            sc[n] = scaleC[col];
            sh[n] = shiftC[col];
        }
        __syncthreads();
        #pragma unroll
        for (int m = 0; m < 4; ++m) {
            int rowb = m * 16 + (lane >> 4) * 4;
            #pragma unroll
            for (int n = 0; n < 4; ++n) {
                int col = wcol + n * 16 + brow;
                #pragma unroll
                for (int r = 0; r < 4; ++r) {
                    float zn = acc[m][n][r] * sc[n] + sh[n];
                    lds[(rowb + r) * LDZ + col] = (short)f2b(zn);
                }
            }
        }
        __syncthreads();
        const int c0 = (tid & 31) * 4;
        const int r0 = tid >> 5;
        #pragma unroll
        for (int rp = 0; rp < 8; ++rp) {
            int row = rp * 8 + r0;
            int d   = dst[rowBase + row];
            float* ap = agg + (size_t)d * HIDDEN + c0;
            s16x4 f4 = *(const s16x4*)&lds[row * LDZ + c0];
            s16x4 c4 = *(const s16x4*)&lds[row * LDZ + 128 + c0];
            #pragma unroll
            for (int j = 0; j < 4; ++j) {
                float fv  = b2f((unsigned short)f4[j]);
                float cv  = b2f((unsigned short)c4[j]);
                atomicAdd(ap + j, sigmoid_(fv) * softplus_(cv));
            }
        }
    }
}

// ---- per-node gather-reduce: normalize + gate + segment-sum + residual ----
__global__ __launch_bounds__(256)
void node_gather(const short* __restrict__ z, const int* __restrict__ perm,
                 const int* __restrict__ offs, const int* __restrict__ counts,
                 const float* __restrict__ scaleC, const float* __restrict__ shiftC,
                 const float* __restrict__ h, float* __restrict__ out) {
    int node = blockIdx.x * 4 + (threadIdx.x >> 6);
    int lane = threadIdx.x & 63;
    int l32  = lane & 31;
    int c0   = l32 * 4;

    float scF[4], shF[4], scS[4], shS[4];
    #pragma unroll
    for (int k = 0; k < 4; ++k) {
        scF[k] = scaleC[c0 + k];       shF[k] = shiftC[c0 + k];
        scS[k] = scaleC[128 + c0 + k]; shS[k] = shiftC[128 + c0 + k];
    }

    int s   = offs[node];
    int deg = counts[node];
    float a0 = 0.f, a1 = 0.f, a2 = 0.f, a3 = 0.f;

    for (int j = (lane >> 5); j < deg; j += 4) {
        int jB = j + 2;
        bool hasB = (jB < deg);
        int eA = perm[s + j];
        int eB = hasB ? perm[s + jB] : eA;
        const short* zA = z + (size_t)eA * NOUT + c0;
        const short* zB = z + (size_t)eB * NOUT + c0;
        uint2 fA = *(const uint2*)zA;
        uint2 cA = *(const uint2*)(zA + 128);
        uint2 fB = *(const uint2*)zB;
        uint2 cB = *(const uint2*)(zB + 128);

        float f0 = bflo(fA.x) * scF[0] + shF[0];
        float f1 = bfhi(fA.x) * scF[1] + shF[1];
        float f2 = bflo(fA.y) * scF[2] + shF[2];
        float f3 = bfhi(fA.y) * scF[3] + shF[3];
        float g0 = bflo(cA.x) * scS[0] + shS[0];
        float g1 = bfhi(cA.x) * scS[1] + shS[1];
        float g2 = bflo(cA.y) * scS[2] + shS[2];
        float g3 = bfhi(cA.y) * scS[3] + shS[3];
        a0 += sigmoid_(f0) * softplus_(g0);
        a1 += sigmoid_(f1) * softplus_(g1);
        a2 += sigmoid_(f2) * softplus_(g2);
        a3 += sigmoid_(f3) * softplus_(g3);

        if (hasB) {
            f0 = bflo(fB.x) * scF[0] + shF[0];
            f1 = bfhi(fB.x) * scF[1] + shF[1];
            f2 = bflo(fB.y) * scF[2] + shF[2];
            f3 = bfhi(fB.y) * scF[3] + shF[3];
            g0 = bflo(cB.x) * scS[0] + shS[0];
            g1 = bfhi(cB.x) * scS[1] + shS[1];
            g2 = bflo(cB.y) * scS[2] + shS[2];
            g3 = bfhi(cB.y) * scS[3] + shS[3];
            a0 += sigmoid_(f0) * softplus_(g0);
            a1 += sigmoid_(f1) * softplus_(g1);
            a2 += sigmoid_(f2) * softplus_(g2);
            a3 += sigmoid_(f3) * softplus_(g3);
        }
    }
    a0 += __shfl_xor(a0, 32, 64);
    a1 += __shfl_xor(a1, 32, 64);
    a2 += __shfl_xor(a2, 32, 64);
    a3 += __shfl_xor(a3, 32, 64);

    if (lane < 32) {
        size_t o = (size_t)node * HIDDEN + c0;
        float4 hv = *(const float4*)&h[o];
        float4 r;
        r.x = softplus_(hv.x + a0);
        r.y = softplus_(hv.y + a1);
        r.z = softplus_(hv.z + a2);
        r.w = softplus_(hv.w + a3);
        *(float4*)&out[o] = r;
    }
}

// ---- fallback finalize ----------------------------------------------------
__global__ void node_finalize(const float* __restrict__ h, float* __restrict__ out) {
    int i = blockIdx.x * 256 + threadIdx.x;
    float4 hv = ((const float4*)h)[i];
    float4 av = ((float4*)out)[i];
    float4 r;
    r.x = softplus_(hv.x + av.x);
    r.y = softplus_(hv.y + av.y);
    r.z = softplus_(hv.z + av.z);
    r.w = softplus_(hv.w + av.w);
    ((float4*)out)[i] = r;
}

extern "C" void kernel_launch(void* const* d_in, const int* in_sizes, int n_in,
                              void* d_out, int out_size, void* d_ws, size_t ws_size,
                              hipStream_t stream) {
    const float* h     = (const float*)d_in[0];
    const float* e     = (const float*)d_in[1];
    const int*   srcp  = (const int*)d_in[2];
    const int*   dstp  = (const int*)d_in[3];
    const float* W     = (const float*)d_in[4];
    // d_in[5] = b : cancels through BatchNorm
    const float* gamma = (const float*)d_in[6];
    const float* beta  = (const float*)d_in[7];
    float* out = (float*)d_out;

    char*  ws     = (char*)d_ws;
    float* stats  = (float*)ws;                  // 64*512*4 = 131072 B
    float* scaleC = (float*)(ws + 131072);
    float* shiftC = (float*)(ws + 132096);
    short* wt     = (short*)(ws + 133120);       // 196608 B -> 329728
    int*   counts = (int*)(ws + 329728);
    int*   offs   = (int*)(ws + 409856);
    int*   cursor = (int*)(ws + 489984);
    int*   perm   = (int*)(ws + 570112);         // 1.92 MB -> 2490112
    short* zbuf   = (short*)(ws + 2490112);      // 245.76 MB
    const size_t need = 2490112ull + (size_t)N_EDGES * NOUT * 2;

    hipMemsetAsync(stats, 0, 131072, stream);
    convW<<<NOUT, 256, 0, stream>>>(W, wt);

    if (ws_size >= need) {
        hipMemsetAsync(counts, 0, N_NODES * sizeof(int), stream);
        hist_dst<<<(N_EDGES + 255) / 256, 256, 0, stream>>>(dstp, counts);
        scan_nodes<<<1, 1024, 0, stream>>>(counts, offs, cursor);
        build_perm<<<(N_EDGES + 255) / 256, 256, 0, stream>>>(dstp, cursor, perm);

        edge_gemm<0><<<N_EDGES / 64, 256, 0, stream>>>(h, e, srcp, dstp, wt,
                stats, nullptr, nullptr, nullptr, zbuf);
        bn_finalize<<<1, 256, 0, stream>>>(stats, gamma, beta, scaleC, shiftC);
        node_gather<<<N_NODES / 4, 256, 0, stream>>>(zbuf, perm, offs, counts,
                scaleC, shiftC, h, out);
    } else {
        hipMemsetAsync(out, 0, (size_t)N_NODES * HIDDEN * sizeof(float), stream);
        edge_gemm<1><<<N_EDGES / 64, 256, 0, stream>>>(h, e, srcp, dstp, wt,
                stats, nullptr, nullptr, nullptr, nullptr);
        bn_finalize<<<1, 256, 0, stream>>>(stats, gamma, beta, scaleC, shiftC);
        edge_gemm<2><<<N_EDGES / 64, 256, 0, stream>>>(h, e, srcp, dstp, wt,
                stats, scaleC, shiftC, out, nullptr);
        node_finalize<<<N_NODES * HIDDEN / (4 * 256), 256, 0, stream>>>(h, out);
    }
}